// Round 8
// baseline (840.851 us; speedup 1.0000x reference)
//
#include <hip/hip_runtime.h>
#include <hip/hip_cooperative_groups.h>
#include <math.h>

namespace cg = cooperative_groups;

// KGATConv: N=50000, E=800000, D=64, R=16, fp32.
// R14 = R10 base (best verified, 468.7us) with the CSR chain
// (memset+hist+scan1+scan2, 4 dispatches) merged into ONE cooperative
// kernel with grid.sync() phases. 9 -> 6 dispatches; kernel bodies of
// k_proj/k_att/k_agg/k_bi are byte-identical to R10.
// R13's 2-edge k_att regressed (+17us) and is reverted.

#define DIM 64
#define PA 72

typedef _Float16 half8 __attribute__((ext_vector_type(8)));
typedef float f32x4 __attribute__((ext_vector_type(4)));
typedef unsigned int u32x4 __attribute__((ext_vector_type(4)));

__device__ __forceinline__ float4 f4zero() { return make_float4(0.f, 0.f, 0.f, 0.f); }

__device__ __forceinline__ unsigned short f2bf(float x) {
    unsigned u = __float_as_uint(x);
    u += 0x7FFFu + ((u >> 16) & 1u);   // RNE
    return (unsigned short)(u >> 16);
}

__device__ __forceinline__ float fast_tanh(float x) {
    float ex = __expf(2.0f * x);
    return 1.0f - 2.0f / (ex + 1.0f);
}

// unpack 8 bf16 (in a u32x4) to fp32
__device__ __forceinline__ void bf8up(u32x4 u, float* f) {
    f[0] = __uint_as_float(u[0] << 16);
    f[1] = __uint_as_float(u[0] & 0xFFFF0000u);
    f[2] = __uint_as_float(u[1] << 16);
    f[3] = __uint_as_float(u[1] & 0xFFFF0000u);
    f[4] = __uint_as_float(u[2] << 16);
    f[5] = __uint_as_float(u[2] & 0xFFFF0000u);
    f[6] = __uint_as_float(u[3] << 16);
    f[7] = __uint_as_float(u[3] & 0xFFFF0000u);
}

// ---------------------------------------------------------------------------
// Cooperative CSR build: zero deg -> hist(+rank) -> per-chunk scan ->
// block-sum scan -> off. One launch, grid.sync() between phases.
// 1024 blocks x 256 threads (co-resident: low VGPR/LDS, cap 2048).
// ---------------------------------------------------------------------------
__global__ __launch_bounds__(256) void k_csr(const int* __restrict__ dst,
                                             int* __restrict__ deg,
                                             int* __restrict__ rank,
                                             int* __restrict__ epart,
                                             int* __restrict__ bsum,
                                             int* __restrict__ off,
                                             int N, int E) {
    cg::grid_group grid = cg::this_grid();
    __shared__ int sh[256];
    const int tid = blockIdx.x * 256 + threadIdx.x;
    const int nth = gridDim.x * 256;
    const int t = threadIdx.x;
    const int NBn = (N + 255) >> 8;

    // P0: zero deg
    for (int i = tid; i < N; i += nth) deg[i] = 0;
    grid.sync();

    // P1: histogram; atomic return value = within-segment rank (bijective)
    for (int e = tid; e < E; e += nth) rank[e] = atomicAdd(&deg[dst[e]], 1);
    grid.sync();

    // P2: per-256-chunk inclusive scan -> epart (excl-in-chunk) + bsum
    for (int b = blockIdx.x; b < NBn; b += gridDim.x) {
        int i = b * 256 + t;
        int v = (i < N) ? deg[i] : 0;
        sh[t] = v;
        __syncthreads();
#pragma unroll
        for (int d = 1; d < 256; d <<= 1) {
            int o = (t >= d) ? sh[t - d] : 0;
            __syncthreads();
            sh[t] += o;
            __syncthreads();
        }
        if (i < N) epart[i] = sh[t] - v;
        if (t == 255) bsum[b] = sh[255];
        __syncthreads();
    }
    grid.sync();

    // P3: block 0 scans the <=256 block sums to exclusive prefixes
    if (blockIdx.x == 0) {
        int v = (t < NBn) ? bsum[t] : 0;
        sh[t] = v;
        __syncthreads();
#pragma unroll
        for (int d = 1; d < 256; d <<= 1) {
            int o = (t >= d) ? sh[t - d] : 0;
            __syncthreads();
            sh[t] += o;
            __syncthreads();
        }
        if (t < NBn) bsum[t] = sh[t] - v;
    }
    grid.sync();

    // P4: final offsets
    for (int i = tid; i < N; i += nth) off[i] = epart[i] + bsum[i >> 8];
    if (tid == 0) off[N] = E;
}

// ---------------------------------------------------------------------------
// proj[r,n,:] = bf16( nfeat[n,:] @ relW[r,:,:] ) via mfma_f32_16x16x32_f16
// A-tile + fragments loaded once; each block loops over R/4 relations.
// Output bounced through LDS -> coalesced 16B stores.
// ---------------------------------------------------------------------------
__global__ __launch_bounds__(256) void k_proj(const float* __restrict__ nfeat,
                                              const float* __restrict__ relW,
                                              unsigned short* __restrict__ proj,
                                              int N, int R) {
    __shared__ _Float16 shA[64 * PA];
    __shared__ _Float16 shB[64 * PA];
    unsigned short* shSt = (unsigned short*)shA;   // store-staging (shA dead after frag load)

    const int tx = threadIdx.x;
    const int n0 = blockIdx.x * 64;
    const int rpb = R >> 2;                 // relations per block (grid.y == 4)
    const int rb = blockIdx.y * rpb;

    const float4* nf4 = (const float4*)(nfeat + (size_t)n0 * DIM);
#pragma unroll
    for (int i = 0; i < 4; ++i) {
        int idx = tx + 256 * i;
        int row = idx >> 4, c = idx & 15;
        float4 v = (n0 + row < N) ? nf4[idx] : f4zero();
        _Float16* p = &shA[row * PA + c * 4];
        p[0] = (_Float16)v.x; p[1] = (_Float16)v.y;
        p[2] = (_Float16)v.z; p[3] = (_Float16)v.w;
    }
    __syncthreads();

    const int w = tx >> 6;
    const int lane = tx & 63;
    const int lm = lane & 15;
    const int lq = lane >> 4;
    const int m0 = w * 16;

    // A fragments are relation-independent: load once.
    half8 a0 = *(const half8*)&shA[(m0 + lm) * PA + 0 * 32 + lq * 8];
    half8 a1 = *(const half8*)&shA[(m0 + lm) * PA + 1 * 32 + lq * 8];

    for (int rr = 0; rr < rpb; ++rr) {
        const int r = rb + rr;
        __syncthreads();   // prev iter's shB mfma-reads + shSt store-reads complete
        const float4* Wr4 = (const float4*)(relW + (size_t)r * DIM * DIM);
#pragma unroll
        for (int i = 0; i < 4; ++i) {
            int idx = tx + 256 * i;
            int d = idx >> 4, c = (idx & 15) * 4;
            float4 v = Wr4[idx];
            shB[(c + 0) * PA + d] = (_Float16)v.x;
            shB[(c + 1) * PA + d] = (_Float16)v.y;
            shB[(c + 2) * PA + d] = (_Float16)v.z;
            shB[(c + 3) * PA + d] = (_Float16)v.w;
        }
        __syncthreads();

        f32x4 acc[4];
#pragma unroll
        for (int ct = 0; ct < 4; ++ct) {
            half8 b0 = *(const half8*)&shB[(ct * 16 + lm) * PA + 0 * 32 + lq * 8];
            half8 b1 = *(const half8*)&shB[(ct * 16 + lm) * PA + 1 * 32 + lq * 8];
            f32x4 c = {0.f, 0.f, 0.f, 0.f};
            c = __builtin_amdgcn_mfma_f32_16x16x32_f16(a0, b0, c, 0, 0, 0);
            c = __builtin_amdgcn_mfma_f32_16x16x32_f16(a1, b1, c, 0, 0, 0);
            acc[ct] = c;
        }

        // stage bf16 result in LDS (row stride 72 ushort -> 144B, 16B aligned)
#pragma unroll
        for (int ct = 0; ct < 4; ++ct) {
#pragma unroll
            for (int i = 0; i < 4; ++i) {
                int row = m0 + lq * 4 + i;
                int col = ct * 16 + lm;
                shSt[row * PA + col] = f2bf(acc[ct][i]);
            }
        }
        __syncthreads();

        // coalesced stores: 512 x 16B chunks, 2 per thread; wave covers 1KB
        unsigned short* projR = proj + ((size_t)r * N + n0) * DIM;
#pragma unroll
        for (int k = 0; k < 2; ++k) {
            int chunk = tx + k * 256;
            int row = chunk >> 3, cc = chunk & 7;
            uint4 v = *(const uint4*)&shSt[row * PA + cc * 8];
            if (n0 + row < N)
                *(uint4*)&projR[(size_t)row * DIM + cc * 8] = v;
        }
    }
}

// ---------------------------------------------------------------------------
// Attention, 8 threads per edge. p = off[dst] + rank (atomic-free slot).
// ---------------------------------------------------------------------------
__global__ __launch_bounds__(256) void k_att(const unsigned short* __restrict__ proj,
                                             const float* __restrict__ efeat,
                                             const int* __restrict__ src,
                                             const int* __restrict__ dst,
                                             const int* __restrict__ etype,
                                             const int* __restrict__ rank,
                                             const int* __restrict__ off,
                                             float* __restrict__ att_s,
                                             int* __restrict__ src_s,
                                             int N, int E) {
    int t = blockIdx.x * 256 + threadIdx.x;
    int e = t >> 3;
    int sub = t & 7;
    if (e >= E) return;
    int s = src[e], d = dst[e], r = etype[e];

    const u32x4* tp = (const u32x4*)(proj + ((size_t)((unsigned)(r * N + s))) * DIM) + sub;
    const u32x4* hp = (const u32x4*)(proj + ((size_t)((unsigned)(r * N + d))) * DIM) + sub;
    const f32x4* ef = (const f32x4*)(efeat + (size_t)e * DIM) + sub * 2;

    u32x4 tu = *tp;
    u32x4 hu = *hp;
    f32x4 efa = __builtin_nontemporal_load(ef);
    f32x4 efb = __builtin_nontemporal_load(ef + 1);

    float tf[8], hf[8];
    bf8up(tu, tf);
    bf8up(hu, hf);
    float ev[8] = {efa[0], efa[1], efa[2], efa[3], efb[0], efb[1], efb[2], efb[3]};

    float dotv = 0.f;
#pragma unroll
    for (int i = 0; i < 8; ++i)
        dotv = fmaf(tf[i], fast_tanh(hf[i] + ev[i]), dotv);

    dotv += __shfl_xor(dotv, 1);
    dotv += __shfl_xor(dotv, 2);
    dotv += __shfl_xor(dotv, 4);

    int p = off[d] + rank[e];
    if (sub == 0) att_s[p] = dotv;
    if (sub == 1) src_s[p] = s;
}

// ---------------------------------------------------------------------------
// Pure softmax + aggregation. Wave per node, NO LDS.
// Quarter-wave float4 gathers: one VMEM instr covers 4 nfeat rows.
// ---------------------------------------------------------------------------
__global__ __launch_bounds__(256) void k_agg(const float* __restrict__ att_s,
                                             const int* __restrict__ src_s,
                                             const float* __restrict__ nfeat,
                                             const int* __restrict__ off,
                                             float* __restrict__ hn, int N) {
    const int node = blockIdx.x * 4 + (threadIdx.x >> 6);
    if (node >= N) return;
    const int lane = threadIdx.x & 63;
    const int qw = lane >> 4;   // quarter-wave index (row slot)
    const int ql = lane & 15;   // lane within quarter (4-dim slice)

    const int jb = off[node];
    const int je = off[node + 1];

    float m = -INFINITY;
    for (int j0 = jb; j0 < je; j0 += 64) {
        int j = j0 + lane;
        float a = (j < je) ? att_s[j] : -INFINITY;
        m = fmaxf(m, a);
    }
#pragma unroll
    for (int ms = 32; ms; ms >>= 1) m = fmaxf(m, __shfl_xor(m, ms));

    float pl = 0.f;
    f32x4 acc = {0.f, 0.f, 0.f, 0.f};
    for (int j0 = jb; j0 < je; j0 += 64) {
        int j = j0 + lane;
        int cnt = min(64, je - j0);
        float a = (j < je) ? att_s[j] : -INFINITY;
        float p = __expf(a - m);
        int s = (j < je) ? src_s[j] : 0;
        pl += p;

        int jj = 0;
        for (; jj + 15 < cnt; jj += 16) {
            float pj[4]; int sj[4]; f32x4 x[4];
#pragma unroll
            for (int u = 0; u < 4; ++u) {
                int eidx = jj + u * 4 + qw;
                pj[u] = __shfl(p, eidx);
                sj[u] = __shfl(s, eidx);
            }
#pragma unroll
            for (int u = 0; u < 4; ++u)
                x[u] = *(const f32x4*)&nfeat[(size_t)sj[u] * DIM + ql * 4];
#pragma unroll
            for (int u = 0; u < 4; ++u) {
                acc[0] = fmaf(pj[u], x[u][0], acc[0]);
                acc[1] = fmaf(pj[u], x[u][1], acc[1]);
                acc[2] = fmaf(pj[u], x[u][2], acc[2]);
                acc[3] = fmaf(pj[u], x[u][3], acc[3]);
            }
        }
        for (; jj < cnt; jj += 4) {
            int eidx = jj + qw;
            int ec = (eidx < cnt) ? eidx : (cnt - 1);
            float pj = __shfl(p, ec);
            int sj = __shfl(s, ec);
            if (eidx < cnt) {
                f32x4 x = *(const f32x4*)&nfeat[(size_t)sj * DIM + ql * 4];
                acc[0] = fmaf(pj, x[0], acc[0]);
                acc[1] = fmaf(pj, x[1], acc[1]);
                acc[2] = fmaf(pj, x[2], acc[2]);
                acc[3] = fmaf(pj, x[3], acc[3]);
            }
        }
    }
#pragma unroll
    for (int ms = 32; ms; ms >>= 1) pl += __shfl_xor(pl, ms);

#pragma unroll
    for (int c = 0; c < 4; ++c) {
        acc[c] += __shfl_xor(acc[c], 16);
        acc[c] += __shfl_xor(acc[c], 32);
    }

    const float inv = (je > jb) ? 1.0f / pl : 0.f;
    if (qw == 0) {
        f32x4 hv = {acc[0] * inv, acc[1] * inv, acc[2] * inv, acc[3] * inv};
        *(f32x4*)&hn[(size_t)node * DIM + ql * 4] = hv;
    }
}

// ---------------------------------------------------------------------------
// Bi-interaction: out = lrelu((nf+hn)@W1) + lrelu((nf*hn)@W2), MFMA f16.
// ---------------------------------------------------------------------------
__global__ __launch_bounds__(256) void k_bi(const float* __restrict__ nfeat,
                                            const float* __restrict__ hn,
                                            const float* __restrict__ W1,
                                            const float* __restrict__ W2,
                                            float* __restrict__ out, int N) {
    __shared__ _Float16 shMem[4 * 64 * PA];
    _Float16* shA1 = shMem;
    _Float16* shA2 = shMem + 64 * PA;
    _Float16* shB1 = shMem + 2 * 64 * PA;
    _Float16* shB2 = shMem + 3 * 64 * PA;

    const int tx = threadIdx.x;
    const int n0 = blockIdx.x * 64;

    const float4* nf4 = (const float4*)(nfeat + (size_t)n0 * DIM);
    const float4* hn4 = (const float4*)(hn + (size_t)n0 * DIM);
#pragma unroll
    for (int i = 0; i < 4; ++i) {
        int idx = tx + 256 * i;
        int row = idx >> 4, c = idx & 15;
        bool ok = (n0 + row < N);
        float4 a = ok ? nf4[idx] : f4zero();
        float4 b = ok ? hn4[idx] : f4zero();
        _Float16* p1 = &shA1[row * PA + c * 4];
        _Float16* p2 = &shA2[row * PA + c * 4];
        p1[0] = (_Float16)(a.x + b.x); p2[0] = (_Float16)(a.x * b.x);
        p1[1] = (_Float16)(a.y + b.y); p2[1] = (_Float16)(a.y * b.y);
        p1[2] = (_Float16)(a.z + b.z); p2[2] = (_Float16)(a.z * b.z);
        p1[3] = (_Float16)(a.w + b.w); p2[3] = (_Float16)(a.w * b.w);
    }
    const float4* w14 = (const float4*)W1;
    const float4* w24 = (const float4*)W2;
#pragma unroll
    for (int i = 0; i < 4; ++i) {
        int idx = tx + 256 * i;
        int k = idx >> 4, c = (idx & 15) * 4;
        float4 v = w14[idx];
        shB1[(c + 0) * PA + k] = (_Float16)v.x;
        shB1[(c + 1) * PA + k] = (_Float16)v.y;
        shB1[(c + 2) * PA + k] = (_Float16)v.z;
        shB1[(c + 3) * PA + k] = (_Float16)v.w;
        float4 u = w24[idx];
        shB2[(c + 0) * PA + k] = (_Float16)u.x;
        shB2[(c + 1) * PA + k] = (_Float16)u.y;
        shB2[(c + 2) * PA + k] = (_Float16)u.z;
        shB2[(c + 3) * PA + k] = (_Float16)u.w;
    }
    __syncthreads();

    const int w = tx >> 6;
    const int lane = tx & 63;
    const int lm = lane & 15;
    const int lq = lane >> 4;
    const int m0 = w * 16;

    half8 a10 = *(const half8*)&shA1[(m0 + lm) * PA + lq * 8];
    half8 a11 = *(const half8*)&shA1[(m0 + lm) * PA + 32 + lq * 8];
    half8 a20 = *(const half8*)&shA2[(m0 + lm) * PA + lq * 8];
    half8 a21 = *(const half8*)&shA2[(m0 + lm) * PA + 32 + lq * 8];

    f32x4 res[4];
#pragma unroll
    for (int ct = 0; ct < 4; ++ct) {
        half8 b10 = *(const half8*)&shB1[(ct * 16 + lm) * PA + lq * 8];
        half8 b11 = *(const half8*)&shB1[(ct * 16 + lm) * PA + 32 + lq * 8];
        half8 b20 = *(const half8*)&shB2[(ct * 16 + lm) * PA + lq * 8];
        half8 b21 = *(const half8*)&shB2[(ct * 16 + lm) * PA + 32 + lq * 8];
        f32x4 c1 = {0.f, 0.f, 0.f, 0.f};
        f32x4 c2 = {0.f, 0.f, 0.f, 0.f};
        c1 = __builtin_amdgcn_mfma_f32_16x16x32_f16(a10, b10, c1, 0, 0, 0);
        c1 = __builtin_amdgcn_mfma_f32_16x16x32_f16(a11, b11, c1, 0, 0, 0);
        c2 = __builtin_amdgcn_mfma_f32_16x16x32_f16(a20, b20, c2, 0, 0, 0);
        c2 = __builtin_amdgcn_mfma_f32_16x16x32_f16(a21, b21, c2, 0, 0, 0);
#pragma unroll
        for (int i = 0; i < 4; ++i) {
            float o1 = c1[i], o2 = c2[i];
            res[ct][i] = (o1 >= 0.f ? o1 : 0.01f * o1) + (o2 >= 0.f ? o2 : 0.01f * o2);
        }
    }

    __syncthreads();
    float* shSt = (float*)shMem;   // 64*68*4 = 17408B <= 36864B
#pragma unroll
    for (int ct = 0; ct < 4; ++ct)
#pragma unroll
        for (int i = 0; i < 4; ++i)
            shSt[(m0 + lq * 4 + i) * 68 + ct * 16 + lm] = res[ct][i];
    __syncthreads();

    float* outp = out + (size_t)n0 * DIM;
#pragma unroll
    for (int k = 0; k < 4; ++k) {
        int idx = tx + 256 * k;
        int row = idx >> 4, cc = idx & 15;
        if (n0 + row < N) {
            float4 v = *(const float4*)&shSt[row * 68 + cc * 4];
            *(float4*)&outp[(size_t)row * DIM + cc * 4] = v;
        }
    }
}

extern "C" void kernel_launch(void* const* d_in, const int* in_sizes, int n_in,
                              void* d_out, int out_size, void* d_ws, size_t ws_size,
                              hipStream_t stream) {
    const float* nfeat = (const float*)d_in[0];
    const float* efeat = (const float*)d_in[1];
    const float* relW  = (const float*)d_in[2];
    const float* W1    = (const float*)d_in[3];
    const float* W2    = (const float*)d_in[4];
    const int* src   = (const int*)d_in[5];
    const int* dst   = (const int*)d_in[6];
    const int* etype = (const int*)d_in[7];

    const int N = in_sizes[0] / DIM;
    const int E = in_sizes[5];
    const int R = in_sizes[2] / (DIM * DIM);

    float* out = (float*)d_out;
    float* hn  = out;
    float* bi  = out + (size_t)N * DIM;

    // ws: proj bf16 | deg[N] | off[N+1] | epart[N] | bsum[256] | rank[E] | src_s[E] | att_s[E]
    unsigned short* proj = (unsigned short*)d_ws;
    size_t projElems = (size_t)R * N * DIM;
    int* deg    = (int*)(proj + projElems);
    int* off    = deg + N;
    int* epart  = off + (N + 1);
    int* bsum   = epart + N;
    int* rank   = bsum + 256;
    int* src_s  = rank + E;
    float* att_s = (float*)(src_s + E);

    // one cooperative kernel replaces memset + hist + scan1 + scan2
    {
        int Nv = N, Ev = E;
        void* args[] = {(void*)&dst, (void*)&deg, (void*)&rank, (void*)&epart,
                        (void*)&bsum, (void*)&off, (void*)&Nv, (void*)&Ev};
        (void)hipLaunchCooperativeKernel((void*)k_csr, dim3(1024), dim3(256),
                                         args, 0, stream);
    }

    dim3 gProj((N + 63) / 64, 4);
    k_proj<<<gProj, 256, 0, stream>>>(nfeat, relW, proj, N, R);

    k_att<<<((size_t)E * 8 + 255) / 256, 256, 0, stream>>>(proj, efeat, src, dst, etype,
                                                           rank, off, att_s, src_s, N, E);

    k_agg<<<(N + 3) / 4, 256, 0, stream>>>(att_s, src_s, nfeat, off, hn, N);

    k_bi<<<(N + 63) / 64, 256, 0, stream>>>(nfeat, hn, W1, W2, bi, N);
}

// Round 9
// 467.744 us; speedup vs baseline: 1.7977x; 1.7977x over previous
//
#include <hip/hip_runtime.h>
#include <math.h>

// KGATConv: N=50000, E=800000, D=64, R=16, fp32.
// R15 = exact revert to R10 (best verified: 468.7us).
// Failed-experiment ledger (do not retry):
//   R11/R12: fused MFMA attention (proj-table-free) -> 157/202us vs 95us.
//   R13: 2-edges-per-8-lane k_att (2x MLP) -> +17us (VGPR/occupancy cost).
//   R14: cooperative-kernel CSR merge -> grid.sync costs ~80us each on
//        gfx950 at 1024 blocks; k_csr alone 399us. Launch gaps are small
//        (R10 CSR chain incl. launches = ~28us total).
// Budget at R10: fill ~242 (harness) + CSR 28 + proj ~60 + att ~95 +
//                agg ~30 + bi ~12.

#define DIM 64
#define PA 72

typedef _Float16 half8 __attribute__((ext_vector_type(8)));
typedef float f32x4 __attribute__((ext_vector_type(4)));
typedef unsigned int u32x4 __attribute__((ext_vector_type(4)));

__device__ __forceinline__ float4 f4zero() { return make_float4(0.f, 0.f, 0.f, 0.f); }

__device__ __forceinline__ unsigned short f2bf(float x) {
    unsigned u = __float_as_uint(x);
    u += 0x7FFFu + ((u >> 16) & 1u);   // RNE
    return (unsigned short)(u >> 16);
}

__device__ __forceinline__ float fast_tanh(float x) {
    float ex = __expf(2.0f * x);
    return 1.0f - 2.0f / (ex + 1.0f);
}

// unpack 8 bf16 (in a u32x4) to fp32
__device__ __forceinline__ void bf8up(u32x4 u, float* f) {
    f[0] = __uint_as_float(u[0] << 16);
    f[1] = __uint_as_float(u[0] & 0xFFFF0000u);
    f[2] = __uint_as_float(u[1] << 16);
    f[3] = __uint_as_float(u[1] & 0xFFFF0000u);
    f[4] = __uint_as_float(u[2] << 16);
    f[5] = __uint_as_float(u[2] & 0xFFFF0000u);
    f[6] = __uint_as_float(u[3] << 16);
    f[7] = __uint_as_float(u[3] & 0xFFFF0000u);
}

// ---------------------------------------------------------------------------
// proj[r,n,:] = bf16( nfeat[n,:] @ relW[r,:,:] ) via mfma_f32_16x16x32_f16
// A-tile + fragments loaded once; each block loops over R/4 relations
// (blockIdx.y selects the quarter). Output bounced through LDS -> 16B stores.
// ---------------------------------------------------------------------------
__global__ __launch_bounds__(256) void k_proj(const float* __restrict__ nfeat,
                                              const float* __restrict__ relW,
                                              unsigned short* __restrict__ proj,
                                              int N, int R) {
    __shared__ _Float16 shA[64 * PA];
    __shared__ _Float16 shB[64 * PA];
    unsigned short* shSt = (unsigned short*)shA;   // store-staging (shA dead after frag load)

    const int tx = threadIdx.x;
    const int n0 = blockIdx.x * 64;
    const int rpb = R >> 2;                 // relations per block (grid.y == 4)
    const int rb = blockIdx.y * rpb;

    const float4* nf4 = (const float4*)(nfeat + (size_t)n0 * DIM);
#pragma unroll
    for (int i = 0; i < 4; ++i) {
        int idx = tx + 256 * i;
        int row = idx >> 4, c = idx & 15;
        float4 v = (n0 + row < N) ? nf4[idx] : f4zero();
        _Float16* p = &shA[row * PA + c * 4];
        p[0] = (_Float16)v.x; p[1] = (_Float16)v.y;
        p[2] = (_Float16)v.z; p[3] = (_Float16)v.w;
    }
    __syncthreads();

    const int w = tx >> 6;
    const int lane = tx & 63;
    const int lm = lane & 15;
    const int lq = lane >> 4;
    const int m0 = w * 16;

    // A fragments are relation-independent: load once.
    half8 a0 = *(const half8*)&shA[(m0 + lm) * PA + 0 * 32 + lq * 8];
    half8 a1 = *(const half8*)&shA[(m0 + lm) * PA + 1 * 32 + lq * 8];

    for (int rr = 0; rr < rpb; ++rr) {
        const int r = rb + rr;
        __syncthreads();   // prev iter's shB mfma-reads + shSt store-reads complete
        const float4* Wr4 = (const float4*)(relW + (size_t)r * DIM * DIM);
#pragma unroll
        for (int i = 0; i < 4; ++i) {
            int idx = tx + 256 * i;
            int d = idx >> 4, c = (idx & 15) * 4;
            float4 v = Wr4[idx];
            shB[(c + 0) * PA + d] = (_Float16)v.x;
            shB[(c + 1) * PA + d] = (_Float16)v.y;
            shB[(c + 2) * PA + d] = (_Float16)v.z;
            shB[(c + 3) * PA + d] = (_Float16)v.w;
        }
        __syncthreads();

        f32x4 acc[4];
#pragma unroll
        for (int ct = 0; ct < 4; ++ct) {
            half8 b0 = *(const half8*)&shB[(ct * 16 + lm) * PA + 0 * 32 + lq * 8];
            half8 b1 = *(const half8*)&shB[(ct * 16 + lm) * PA + 1 * 32 + lq * 8];
            f32x4 c = {0.f, 0.f, 0.f, 0.f};
            c = __builtin_amdgcn_mfma_f32_16x16x32_f16(a0, b0, c, 0, 0, 0);
            c = __builtin_amdgcn_mfma_f32_16x16x32_f16(a1, b1, c, 0, 0, 0);
            acc[ct] = c;
        }

        // stage bf16 result in LDS (row stride 72 ushort -> 144B, 16B aligned)
#pragma unroll
        for (int ct = 0; ct < 4; ++ct) {
#pragma unroll
            for (int i = 0; i < 4; ++i) {
                int row = m0 + lq * 4 + i;
                int col = ct * 16 + lm;
                shSt[row * PA + col] = f2bf(acc[ct][i]);
            }
        }
        __syncthreads();

        // coalesced stores: 512 x 16B chunks, 2 per thread; wave covers 1KB
        unsigned short* projR = proj + ((size_t)r * N + n0) * DIM;
#pragma unroll
        for (int k = 0; k < 2; ++k) {
            int chunk = tx + k * 256;
            int row = chunk >> 3, cc = chunk & 7;
            uint4 v = *(const uint4*)&shSt[row * PA + cc * 8];
            if (n0 + row < N)
                *(uint4*)&projR[(size_t)row * DIM + cc * 8] = v;
        }
    }
}

// ---------------------------------------------------------------------------
// CSR build: k_hist's atomic return value is the within-segment rank.
// ---------------------------------------------------------------------------
__global__ __launch_bounds__(256) void k_hist(const int* __restrict__ dst,
                                              int* __restrict__ deg,
                                              int* __restrict__ rank, int E) {
    int e = blockIdx.x * 256 + threadIdx.x;
    if (e < E) rank[e] = atomicAdd(&deg[dst[e]], 1);
}

__global__ __launch_bounds__(256) void k_scan1(const int* __restrict__ deg,
                                               int* __restrict__ epart,
                                               int* __restrict__ bsum, int N) {
    __shared__ int sh[256];
    int i = blockIdx.x * 256 + threadIdx.x;
    int t = threadIdx.x;
    int v = (i < N) ? deg[i] : 0;
    sh[t] = v;
    __syncthreads();
#pragma unroll
    for (int d = 1; d < 256; d <<= 1) {
        int o = (t >= d) ? sh[t - d] : 0;
        __syncthreads();
        sh[t] += o;
        __syncthreads();
    }
    if (i < N) epart[i] = sh[t] - v;
    if (t == 255) bsum[blockIdx.x] = sh[255];
}

__global__ __launch_bounds__(1024) void k_scan2(const int* __restrict__ epart,
                                                const int* __restrict__ bsum,
                                                int nb,
                                                int* __restrict__ off,
                                                int N, int E) {
    __shared__ int bx[256];
    int t = threadIdx.x;
    int v = 0;
    if (t < 256) {
        v = (t < nb) ? bsum[t] : 0;
        bx[t] = v;
    }
    __syncthreads();
#pragma unroll
    for (int d = 1; d < 256; d <<= 1) {
        int o = 0;
        if (t < 256 && t >= d) o = bx[t - d];
        __syncthreads();
        if (t < 256) bx[t] += o;
        __syncthreads();
    }
    if (t < 256) bx[t] -= v;   // exclusive block prefix
    __syncthreads();
    for (int i = t; i < N; i += 1024)
        off[i] = epart[i] + bx[i >> 8];
    if (t == 0) off[N] = E;
}

// ---------------------------------------------------------------------------
// Attention, 8 threads per edge. p = off[dst] + rank (atomic-free slot).
// ---------------------------------------------------------------------------
__global__ __launch_bounds__(256) void k_att(const unsigned short* __restrict__ proj,
                                             const float* __restrict__ efeat,
                                             const int* __restrict__ src,
                                             const int* __restrict__ dst,
                                             const int* __restrict__ etype,
                                             const int* __restrict__ rank,
                                             const int* __restrict__ off,
                                             float* __restrict__ att_s,
                                             int* __restrict__ src_s,
                                             int N, int E) {
    int t = blockIdx.x * 256 + threadIdx.x;
    int e = t >> 3;
    int sub = t & 7;
    if (e >= E) return;
    int s = src[e], d = dst[e], r = etype[e];

    const u32x4* tp = (const u32x4*)(proj + ((size_t)((unsigned)(r * N + s))) * DIM) + sub;
    const u32x4* hp = (const u32x4*)(proj + ((size_t)((unsigned)(r * N + d))) * DIM) + sub;
    const f32x4* ef = (const f32x4*)(efeat + (size_t)e * DIM) + sub * 2;

    u32x4 tu = *tp;
    u32x4 hu = *hp;
    f32x4 efa = __builtin_nontemporal_load(ef);
    f32x4 efb = __builtin_nontemporal_load(ef + 1);

    float tf[8], hf[8];
    bf8up(tu, tf);
    bf8up(hu, hf);
    float ev[8] = {efa[0], efa[1], efa[2], efa[3], efb[0], efb[1], efb[2], efb[3]};

    float dotv = 0.f;
#pragma unroll
    for (int i = 0; i < 8; ++i)
        dotv = fmaf(tf[i], fast_tanh(hf[i] + ev[i]), dotv);

    dotv += __shfl_xor(dotv, 1);
    dotv += __shfl_xor(dotv, 2);
    dotv += __shfl_xor(dotv, 4);

    int p = off[d] + rank[e];
    if (sub == 0) att_s[p] = dotv;
    if (sub == 1) src_s[p] = s;
}

// ---------------------------------------------------------------------------
// Pure softmax + aggregation. Wave per node, NO LDS.
// Quarter-wave float4 gathers: one VMEM instr covers 4 nfeat rows.
// ---------------------------------------------------------------------------
__global__ __launch_bounds__(256) void k_agg(const float* __restrict__ att_s,
                                             const int* __restrict__ src_s,
                                             const float* __restrict__ nfeat,
                                             const int* __restrict__ off,
                                             float* __restrict__ hn, int N) {
    const int node = blockIdx.x * 4 + (threadIdx.x >> 6);
    if (node >= N) return;
    const int lane = threadIdx.x & 63;
    const int qw = lane >> 4;   // quarter-wave index (row slot)
    const int ql = lane & 15;   // lane within quarter (4-dim slice)

    const int jb = off[node];
    const int je = off[node + 1];

    float m = -INFINITY;
    for (int j0 = jb; j0 < je; j0 += 64) {
        int j = j0 + lane;
        float a = (j < je) ? att_s[j] : -INFINITY;
        m = fmaxf(m, a);
    }
#pragma unroll
    for (int ms = 32; ms; ms >>= 1) m = fmaxf(m, __shfl_xor(m, ms));

    float pl = 0.f;
    f32x4 acc = {0.f, 0.f, 0.f, 0.f};
    for (int j0 = jb; j0 < je; j0 += 64) {
        int j = j0 + lane;
        int cnt = min(64, je - j0);
        float a = (j < je) ? att_s[j] : -INFINITY;
        float p = __expf(a - m);
        int s = (j < je) ? src_s[j] : 0;
        pl += p;

        int jj = 0;
        for (; jj + 15 < cnt; jj += 16) {
            float pj[4]; int sj[4]; f32x4 x[4];
#pragma unroll
            for (int u = 0; u < 4; ++u) {
                int eidx = jj + u * 4 + qw;
                pj[u] = __shfl(p, eidx);
                sj[u] = __shfl(s, eidx);
            }
#pragma unroll
            for (int u = 0; u < 4; ++u)
                x[u] = *(const f32x4*)&nfeat[(size_t)sj[u] * DIM + ql * 4];
#pragma unroll
            for (int u = 0; u < 4; ++u) {
                acc[0] = fmaf(pj[u], x[u][0], acc[0]);
                acc[1] = fmaf(pj[u], x[u][1], acc[1]);
                acc[2] = fmaf(pj[u], x[u][2], acc[2]);
                acc[3] = fmaf(pj[u], x[u][3], acc[3]);
            }
        }
        for (; jj < cnt; jj += 4) {
            int eidx = jj + qw;
            int ec = (eidx < cnt) ? eidx : (cnt - 1);
            float pj = __shfl(p, ec);
            int sj = __shfl(s, ec);
            if (eidx < cnt) {
                f32x4 x = *(const f32x4*)&nfeat[(size_t)sj * DIM + ql * 4];
                acc[0] = fmaf(pj, x[0], acc[0]);
                acc[1] = fmaf(pj, x[1], acc[1]);
                acc[2] = fmaf(pj, x[2], acc[2]);
                acc[3] = fmaf(pj, x[3], acc[3]);
            }
        }
    }
#pragma unroll
    for (int ms = 32; ms; ms >>= 1) pl += __shfl_xor(pl, ms);

#pragma unroll
    for (int c = 0; c < 4; ++c) {
        acc[c] += __shfl_xor(acc[c], 16);
        acc[c] += __shfl_xor(acc[c], 32);
    }

    const float inv = (je > jb) ? 1.0f / pl : 0.f;
    if (qw == 0) {
        f32x4 hv = {acc[0] * inv, acc[1] * inv, acc[2] * inv, acc[3] * inv};
        *(f32x4*)&hn[(size_t)node * DIM + ql * 4] = hv;
    }
}

// ---------------------------------------------------------------------------
// Bi-interaction: out = lrelu((nf+hn)@W1) + lrelu((nf*hn)@W2), MFMA f16.
// ---------------------------------------------------------------------------
__global__ __launch_bounds__(256) void k_bi(const float* __restrict__ nfeat,
                                            const float* __restrict__ hn,
                                            const float* __restrict__ W1,
                                            const float* __restrict__ W2,
                                            float* __restrict__ out, int N) {
    __shared__ _Float16 shMem[4 * 64 * PA];
    _Float16* shA1 = shMem;
    _Float16* shA2 = shMem + 64 * PA;
    _Float16* shB1 = shMem + 2 * 64 * PA;
    _Float16* shB2 = shMem + 3 * 64 * PA;

    const int tx = threadIdx.x;
    const int n0 = blockIdx.x * 64;

    const float4* nf4 = (const float4*)(nfeat + (size_t)n0 * DIM);
    const float4* hn4 = (const float4*)(hn + (size_t)n0 * DIM);
#pragma unroll
    for (int i = 0; i < 4; ++i) {
        int idx = tx + 256 * i;
        int row = idx >> 4, c = idx & 15;
        bool ok = (n0 + row < N);
        float4 a = ok ? nf4[idx] : f4zero();
        float4 b = ok ? hn4[idx] : f4zero();
        _Float16* p1 = &shA1[row * PA + c * 4];
        _Float16* p2 = &shA2[row * PA + c * 4];
        p1[0] = (_Float16)(a.x + b.x); p2[0] = (_Float16)(a.x * b.x);
        p1[1] = (_Float16)(a.y + b.y); p2[1] = (_Float16)(a.y * b.y);
        p1[2] = (_Float16)(a.z + b.z); p2[2] = (_Float16)(a.z * b.z);
        p1[3] = (_Float16)(a.w + b.w); p2[3] = (_Float16)(a.w * b.w);
    }
    const float4* w14 = (const float4*)W1;
    const float4* w24 = (const float4*)W2;
#pragma unroll
    for (int i = 0; i < 4; ++i) {
        int idx = tx + 256 * i;
        int k = idx >> 4, c = (idx & 15) * 4;
        float4 v = w14[idx];
        shB1[(c + 0) * PA + k] = (_Float16)v.x;
        shB1[(c + 1) * PA + k] = (_Float16)v.y;
        shB1[(c + 2) * PA + k] = (_Float16)v.z;
        shB1[(c + 3) * PA + k] = (_Float16)v.w;
        float4 u = w24[idx];
        shB2[(c + 0) * PA + k] = (_Float16)u.x;
        shB2[(c + 1) * PA + k] = (_Float16)u.y;
        shB2[(c + 2) * PA + k] = (_Float16)u.z;
        shB2[(c + 3) * PA + k] = (_Float16)u.w;
    }
    __syncthreads();

    const int w = tx >> 6;
    const int lane = tx & 63;
    const int lm = lane & 15;
    const int lq = lane >> 4;
    const int m0 = w * 16;

    half8 a10 = *(const half8*)&shA1[(m0 + lm) * PA + lq * 8];
    half8 a11 = *(const half8*)&shA1[(m0 + lm) * PA + 32 + lq * 8];
    half8 a20 = *(const half8*)&shA2[(m0 + lm) * PA + lq * 8];
    half8 a21 = *(const half8*)&shA2[(m0 + lm) * PA + 32 + lq * 8];

    f32x4 res[4];
#pragma unroll
    for (int ct = 0; ct < 4; ++ct) {
        half8 b10 = *(const half8*)&shB1[(ct * 16 + lm) * PA + lq * 8];
        half8 b11 = *(const half8*)&shB1[(ct * 16 + lm) * PA + 32 + lq * 8];
        half8 b20 = *(const half8*)&shB2[(ct * 16 + lm) * PA + lq * 8];
        half8 b21 = *(const half8*)&shB2[(ct * 16 + lm) * PA + 32 + lq * 8];
        f32x4 c1 = {0.f, 0.f, 0.f, 0.f};
        f32x4 c2 = {0.f, 0.f, 0.f, 0.f};
        c1 = __builtin_amdgcn_mfma_f32_16x16x32_f16(a10, b10, c1, 0, 0, 0);
        c1 = __builtin_amdgcn_mfma_f32_16x16x32_f16(a11, b11, c1, 0, 0, 0);
        c2 = __builtin_amdgcn_mfma_f32_16x16x32_f16(a20, b20, c2, 0, 0, 0);
        c2 = __builtin_amdgcn_mfma_f32_16x16x32_f16(a21, b21, c2, 0, 0, 0);
#pragma unroll
        for (int i = 0; i < 4; ++i) {
            float o1 = c1[i], o2 = c2[i];
            res[ct][i] = (o1 >= 0.f ? o1 : 0.01f * o1) + (o2 >= 0.f ? o2 : 0.01f * o2);
        }
    }

    __syncthreads();
    float* shSt = (float*)shMem;   // 64*68*4 = 17408B <= 36864B
#pragma unroll
    for (int ct = 0; ct < 4; ++ct)
#pragma unroll
        for (int i = 0; i < 4; ++i)
            shSt[(m0 + lq * 4 + i) * 68 + ct * 16 + lm] = res[ct][i];
    __syncthreads();

    float* outp = out + (size_t)n0 * DIM;
#pragma unroll
    for (int k = 0; k < 4; ++k) {
        int idx = tx + 256 * k;
        int row = idx >> 4, cc = idx & 15;
        if (n0 + row < N) {
            float4 v = *(const float4*)&shSt[row * 68 + cc * 4];
            *(float4*)&outp[(size_t)row * DIM + cc * 4] = v;
        }
    }
}

extern "C" void kernel_launch(void* const* d_in, const int* in_sizes, int n_in,
                              void* d_out, int out_size, void* d_ws, size_t ws_size,
                              hipStream_t stream) {
    const float* nfeat = (const float*)d_in[0];
    const float* efeat = (const float*)d_in[1];
    const float* relW  = (const float*)d_in[2];
    const float* W1    = (const float*)d_in[3];
    const float* W2    = (const float*)d_in[4];
    const int* src   = (const int*)d_in[5];
    const int* dst   = (const int*)d_in[6];
    const int* etype = (const int*)d_in[7];

    const int N = in_sizes[0] / DIM;
    const int E = in_sizes[5];
    const int R = in_sizes[2] / (DIM * DIM);
    const int NB = (N + 255) / 256;   // scan blocks (<=256)

    float* out = (float*)d_out;
    float* hn  = out;
    float* bi  = out + (size_t)N * DIM;

    // ws: proj bf16 | deg[N] | off[N+1] | epart[N] | bsum[256] | rank[E] | src_s[E] | att_s[E]
    unsigned short* proj = (unsigned short*)d_ws;
    size_t projElems = (size_t)R * N * DIM;
    int* deg    = (int*)(proj + projElems);
    int* off    = deg + N;
    int* epart  = off + (N + 1);
    int* bsum   = epart + N;
    int* rank   = bsum + 256;
    int* src_s  = rank + E;
    float* att_s = (float*)(src_s + E);

    (void)hipMemsetAsync(deg, 0, (size_t)N * sizeof(int), stream);

    k_hist<<<(E + 255) / 256, 256, 0, stream>>>(dst, deg, rank, E);
    k_scan1<<<NB, 256, 0, stream>>>(deg, epart, bsum, N);
    k_scan2<<<1, 1024, 0, stream>>>(epart, bsum, NB, off, N, E);

    dim3 gProj((N + 63) / 64, 4);
    k_proj<<<gProj, 256, 0, stream>>>(nfeat, relW, proj, N, R);

    k_att<<<((size_t)E * 8 + 255) / 256, 256, 0, stream>>>(proj, efeat, src, dst, etype,
                                                           rank, off, att_s, src_s, N, E);

    k_agg<<<(N + 3) / 4, 256, 0, stream>>>(att_s, src_s, nfeat, off, hn, N);

    k_bi<<<(N + 63) / 64, 256, 0, stream>>>(nfeat, hn, W1, W2, bi, N);
}